// Round 12
// baseline (840.352 us; speedup 1.0000x reference)
//
#include <hip/hip_runtime.h>
#include <math.h>

#define HDIM 1024
#define NWG 128
#define TPB 512
#define CONV_TOL 1.0e-5f

typedef unsigned long long u64;
typedef unsigned int u32;

struct RecArgs {
  const float* whh_l; const float* whh_r;
  const float* glc; const float* glf; const float* grc; const float* grf;
  u64* hq;            // [2][HDIM] tagged slots: low32 = tag | stable<<31, high32 = f32 bits
  float* hsl;         // [n][HDIM]
  float* hsr;         // [n][HDIM]
  const int* pstart; const int* pend;
  int n;
};

// ---------------- setup: target vector, special rows, tagged-state init, accum zeroing ----------------
__global__ void setup_kernel(const int* __restrict__ x, const int* ts, const int* te,
                             const float* __restrict__ emb,
                             float* target, float* seqfl, float* seqfr,
                             u64* hq, float* beta, float* svec, int n) {
  int e = threadIdx.x;  // 0..1023
  int start = ts[0], end = te[0];
  int first_l = (start > 0) ? 0 : (end + 1);
  int first_r = (end < n - 1) ? (n - 1) : (start - 1);
  int fl = min(max(first_l, 0), n - 1);
  int fr = min(max(first_r, 0), n - 1);
  float sum = 0.f;
  for (int p = start; p <= end; ++p) sum += emb[(size_t)x[p] * HDIM + e];
  target[e] = sum / (float)(end - start + 1);
  seqfl[e] = emb[(size_t)x[fl] * HDIM + e];
  seqfr[e] = emb[(size_t)x[fr] * HDIM + e];
  // tag=0 (h input for step 0), value = 0.0f, stable=0 — both parities
  hq[e] = 0ull;
  hq[HDIM + e] = 0ull;
  for (int i = e; i < n; i += 1024) beta[i] = 0.f;
  svec[e] = 0.f;
}

// ---------------- gate-constant vectors: w_ih@v + b_ih + b_hh ----------------
__global__ __launch_bounds__(256) void gateconst_kernel(
    const float* __restrict__ wih_l, const float* bih_l, const float* bhh_l,
    const float* __restrict__ wih_r, const float* bih_r, const float* bhh_r,
    const float* __restrict__ target, const float* __restrict__ seqfl,
    const float* __restrict__ seqfr,
    float* glc, float* glf, float* grc, float* grf) {
  int side = blockIdx.y;
  const float* wih = side ? wih_r : wih_l;
  const float* bih = side ? bih_r : bih_l;
  const float* bhh = side ? bhh_r : bhh_l;
  const float* sf = side ? seqfr : seqfl;
  float* outc = side ? grc : glc;
  float* outf = side ? grf : glf;
  int wv = threadIdx.x >> 6, lane = threadIdx.x & 63;
  int r = blockIdx.x * 4 + wv;  // 0..4095
  const float4* wrow = (const float4*)(wih + (size_t)r * HDIM);
  const float4* tg4 = (const float4*)target;
  const float4* sf4 = (const float4*)sf;
  float dc = 0.f, df = 0.f;
#pragma unroll
  for (int k = 0; k < 4; ++k) {
    float4 w4 = wrow[lane + 64 * k];
    float4 t4 = tg4[lane + 64 * k];
    float4 s4 = sf4[lane + 64 * k];
    dc += w4.x * t4.x + w4.y * t4.y + w4.z * t4.z + w4.w * t4.w;
    df += w4.x * s4.x + w4.y * s4.y + w4.z * s4.z + w4.w * s4.w;
  }
  for (int off = 32; off; off >>= 1) {
    dc += __shfl_xor(dc, off);
    df += __shfl_xor(df, off);
  }
  if (lane == 0) {
    float bb = bih[r] + bhh[r];
    outc[r] = dc + bb;
    outf[r] = df + bb;
  }
}

// ---------------- persistent recurrence ----------------
// R11 structure (TPB=512, poll by threads 0-255, lds_part staging, wave0 epilogue,
// single-wave coalesced lanes<8 publish). R12 delta: PIPELINED 2-DEEP POLL.
// Evidence: R8 (predicated poll) and R11 (TPB split) both NULL -> rec is
// exchange-period-bound at ~1.4-1.6us/step (~250-300 steps from VALUBusy).
// The serial sweep costs up to a full extra LLC-RT of detection lag when a
// publish lands mid-sweep. Keeping a second sweep in flight while checking the
// first halves the effective detection granularity (compiler emits counted
// s_waitcnt vmcnt(N), so sweep B stays outstanding during the A-check).
// Semantics unchanged: tags are monotonic; slots for parity (s&1) are frozen
// until all WGs leave step s, so any sweep that passes the check is valid.
__global__ __launch_bounds__(TPB, 1) void rec_kernel(RecArgs a) {
  const int w = blockIdx.x;
  const int tid = threadIdx.x;
  const int wave = tid >> 6;     // 0..7
  const int lane = tid & 63;
  const int chunk = tid & 31;    // 32-col chunk of the k dimension
  const int rowgrp = tid >> 5;   // 0..15 -> local rows rowgrp*2, rowgrp*2+1
  const int n = a.n;

  __shared__ float lds_h[HDIM];
  __shared__ float lds_part[32 * 36];  // [chunk][row] pitch 36 floats
  __shared__ float lds_h8[2][8];       // [local parity][unit]
  __shared__ int lds_conv[4];

  const int start = a.pstart[0];
  const int end = a.pend[0];
  const int first_l = (start > 0) ? 0 : (end + 1);
  const int first_r = (end < n - 1) ? (n - 1) : (start - 1);

  float4 wreg[2][8];  // constant-indexed only => guaranteed VGPR residency
  float cstate = 0.f;
  float hp0 = 0.f, hp1 = 0.f, cp0 = 0.f, cp1 = 0.f;  // parity history (wave0 lanes<8)

  for (int pass = 0; pass < 2; ++pass) {
    const float* whh = pass ? a.whh_r : a.whh_l;
    const float* gcv = pass ? a.grc : a.glc;
    const float* gfv = pass ? a.grf : a.glf;
    float* hsout = pass ? a.hsr : a.hsl;
    const int tspecial = pass ? (n - 1 - first_r) : first_l;
    const int sbase = pass * n;

#pragma unroll
    for (int r = 0; r < 2; ++r) {
      const int lr = rowgrp * 2 + r;
      const int grow = (lr >> 3) * HDIM + w * 8 + (lr & 7);
      const float4* wr = (const float4*)(whh + (size_t)grow * HDIM) + chunk * 8;
#pragma unroll
      for (int i = 0; i < 8; ++i) wreg[r][i] = wr[(i + chunk) & 7];
    }
    // gate constants for wave0's gate-row mapping: r32 = lane&31 -> gate r32>>3, unit r32&7.
    float my_gc = 0.f, my_gf = 0.f;
    if (wave == 0) {
      const int r32 = lane & 31;
      const int R = (r32 >> 3) * HDIM + w * 8 + (r32 & 7);
      my_gc = gcv[R];
      my_gf = gfv[R];
    }

    bool fin = false;
    for (int t = 0; t < n && !fin; ++t) {
      const int s = sbase + t;
      u64 v0 = 0, v1 = 0, v2 = 0, v3 = 0;
      if (tid < 256) {  // waves 0-3 poll
        const u64* slot = a.hq + (size_t)(s & 1) * HDIM + tid * 4;
        // pipelined 2-deep poll: sweep B is issued before sweep A is consumed,
        // so a publish landing mid-sweep is caught ~RT/2 sooner on average.
        u64 a0, a1, a2, a3, b0, b1, b2, b3;
        a0 = __hip_atomic_load(slot + 0, __ATOMIC_RELAXED, __HIP_MEMORY_SCOPE_AGENT);
        a1 = __hip_atomic_load(slot + 1, __ATOMIC_RELAXED, __HIP_MEMORY_SCOPE_AGENT);
        a2 = __hip_atomic_load(slot + 2, __ATOMIC_RELAXED, __HIP_MEMORY_SCOPE_AGENT);
        a3 = __hip_atomic_load(slot + 3, __ATOMIC_RELAXED, __HIP_MEMORY_SCOPE_AGENT);
        int guard = 0;
        for (;;) {
          b0 = __hip_atomic_load(slot + 0, __ATOMIC_RELAXED, __HIP_MEMORY_SCOPE_AGENT);
          b1 = __hip_atomic_load(slot + 1, __ATOMIC_RELAXED, __HIP_MEMORY_SCOPE_AGENT);
          b2 = __hip_atomic_load(slot + 2, __ATOMIC_RELAXED, __HIP_MEMORY_SCOPE_AGENT);
          b3 = __hip_atomic_load(slot + 3, __ATOMIC_RELAXED, __HIP_MEMORY_SCOPE_AGENT);
          int ok = (((u32)a0 & 0x7fffffffu) >= (u32)s) && (((u32)a1 & 0x7fffffffu) >= (u32)s) &&
                   (((u32)a2 & 0x7fffffffu) >= (u32)s) && (((u32)a3 & 0x7fffffffu) >= (u32)s);
          if (__all(ok)) { v0 = a0; v1 = a1; v2 = a2; v3 = a3; break; }
          a0 = __hip_atomic_load(slot + 0, __ATOMIC_RELAXED, __HIP_MEMORY_SCOPE_AGENT);
          a1 = __hip_atomic_load(slot + 1, __ATOMIC_RELAXED, __HIP_MEMORY_SCOPE_AGENT);
          a2 = __hip_atomic_load(slot + 2, __ATOMIC_RELAXED, __HIP_MEMORY_SCOPE_AGENT);
          a3 = __hip_atomic_load(slot + 3, __ATOMIC_RELAXED, __HIP_MEMORY_SCOPE_AGENT);
          ok = (((u32)b0 & 0x7fffffffu) >= (u32)s) && (((u32)b1 & 0x7fffffffu) >= (u32)s) &&
               (((u32)b2 & 0x7fffffffu) >= (u32)s) && (((u32)b3 & 0x7fffffffu) >= (u32)s);
          if (__all(ok)) { v0 = b0; v1 = b1; v2 = b2; v3 = b3; break; }
          if ((guard += 2) > 4000000) { v0 = a0; v1 = a1; v2 = a2; v3 = a3; break; }
        }
        const u32 t0 = (u32)v0 & 0x7fffffffu, t1 = (u32)v1 & 0x7fffffffu;
        const u32 t2 = (u32)v2 & 0x7fffffffu, t3 = (u32)v3 & 0x7fffffffu;
        int anyg = (t0 > (u32)s) || (t1 > (u32)s) || (t2 > (u32)s) || (t3 > (u32)s);
        int stall = (int)((((u32)v0) >> 31) & (((u32)v1) >> 31) &
                          (((u32)v2) >> 31) & (((u32)v3) >> 31));
        int wany = __any(anyg);
        int wall = __all(stall);
        if (lane == 0) lds_conv[wave] = (wall << 1) | wany;
        float4 hv;
        hv.x = __uint_as_float((u32)(v0 >> 32));
        hv.y = __uint_as_float((u32)(v1 >> 32));
        hv.z = __uint_as_float((u32)(v2 >> 32));
        hv.w = __uint_as_float((u32)(v3 >> 32));
        ((float4*)lds_h)[tid] = hv;
      }
      __syncthreads();  // B1
      const int c0 = lds_conv[0], c1 = lds_conv[1], c2 = lds_conv[2], c3 = lds_conv[3];
      const int convdec = ((c0 | c1 | c2 | c3) & 1) | (((c0 & c1 & c2 & c3) >> 1) & 1);

      if (convdec) {
        const int col = tid & 7;
        for (int tt = t + (tid >> 3); tt < n; tt += 64)
          __builtin_nontemporal_store(lds_h8[tt & 1][col],
                                      &hsout[(size_t)tt * HDIM + w * 8 + col]);
        if (wave == 0 && lane < 8) {
          float hlast = ((n - 1) & 1) ? hp1 : hp0;  // h(n-1)
          float clast = ((n - 1) & 1) ? cp1 : cp0;  // c(n-1)
          cstate = clast;
          u64 pub = (u64)(u32)(sbase + n) | ((u64)__float_as_uint(hlast) << 32);
          __hip_atomic_store(&a.hq[(size_t)((sbase + n) & 1) * HDIM + w * 8 + lane], pub,
                             __ATOMIC_RELAXED, __HIP_MEMORY_SCOPE_AGENT);
        }
        __syncthreads();
        fin = true;
        continue;
      }

      float acc0 = 0.f, acc1 = 0.f;
      const float4* lh4 = (const float4*)lds_h + chunk * 8;
#pragma unroll
      for (int i = 0; i < 8; ++i) {
        float4 h4 = lh4[(i + chunk) & 7];
        acc0 += wreg[0][i].x * h4.x + wreg[0][i].y * h4.y + wreg[0][i].z * h4.z + wreg[0][i].w * h4.w;
        acc1 += wreg[1][i].x * h4.x + wreg[1][i].y * h4.y + wreg[1][i].z * h4.z + wreg[1][i].w * h4.w;
      }
      {
        float2 p; p.x = acc0; p.y = acc1;
        *(float2*)&lds_part[chunk * 36 + rowgrp * 2] = p;  // rows rowgrp*2, +1
      }
      __syncthreads();  // B2

      if (wave == 0) {  // R6 epilogue (bit-identical arithmetic)
        const int r32 = lane & 31;
        const int ccb = (lane >> 5) * 16;
        float sv[16];
#pragma unroll
        for (int cc = 0; cc < 16; ++cc) sv[cc] = lds_part[(ccb + cc) * 36 + r32];
        float sum = (((sv[0] + sv[1]) + (sv[2] + sv[3])) + ((sv[4] + sv[5]) + (sv[6] + sv[7]))) +
                    (((sv[8] + sv[9]) + (sv[10] + sv[11])) + ((sv[12] + sv[13]) + (sv[14] + sv[15])));
        sum += __shfl_xor(sum, 32);
        sum += (t == tspecial) ? my_gf : my_gc;
        const bool is_t = ((r32 >> 3) == 2);
        float xx = is_t ? fminf(fmaxf(sum + sum, -30.f), 30.f) : sum;
        float e = expf(-xx);
        float num = is_t ? (1.f - e) : 1.f;
        float act = num / (1.f + e);
        const int j = lane & 7;
        float iv = __shfl(act, j);
        float fv = __shfl(act, 8 + j);
        float gv = __shfl(act, 16 + j);
        float ov = __shfl(act, 24 + j);
        if (lane < 8) {
          float cnew = fv * cstate + iv * gv;
          float hn = ov * tanhf(cnew);
          float h2 = (t & 1) ? hp1 : hp0;   // h(t-2)
          float c2v = (t & 1) ? cp1 : cp0;  // c(t-2)
          int stab = (fabsf(hn - h2) <= CONV_TOL) &&
                     (fabsf(cnew - c2v) <= CONV_TOL) &&
                     (t > tspecial + 2) && (t >= 32);
          if (t & 1) { hp1 = hn; cp1 = cnew; } else { hp0 = hn; cp0 = cnew; }
          cstate = cnew;
          // publish FIRST — single-wave coalesced 64B publish, the critical property
          u32 tagw = (u32)(s + 1) | ((u32)stab << 31);
          u64 pub = (u64)tagw | ((u64)__float_as_uint(hn) << 32);
          __hip_atomic_store(&a.hq[(size_t)((s + 1) & 1) * HDIM + w * 8 + j], pub,
                             __ATOMIC_RELAXED, __HIP_MEMORY_SCOPE_AGENT);
          lds_h8[t & 1][j] = hn;
          __builtin_nontemporal_store(hn, &hsout[(size_t)t * HDIM + w * 8 + j]);
        }
      }
    }
  }
}

// ---------------- beta via tiled GEMM; lin1_w transposed on the fly during B-staging ----------------
// 64t x 64j tiles, grid (n/64, HDIM/64) = 512 blocks -> 2 blocks/CU. Per-thread
// micro-tile 4t x 4j. Same k-order per (t,j) -> beta bit-identical.
__global__ __launch_bounds__(256) void beta_gemm_kernel(
    const float* __restrict__ hsl, const float* __restrict__ hsr,
    const float* __restrict__ l1w, const float* __restrict__ b1,
    const float* __restrict__ u, float* __restrict__ beta) {
  __shared__ float As[32][64];
  __shared__ float Bs[32][64];
  const int tid = threadIdx.x;
  const int t0 = blockIdx.x * 64;
  const int j0 = blockIdx.y * 64;
  const int tm = tid >> 4;       // 0..15 -> rows t0 + tm*4 .. +3
  const int tj = tid & 15;       // 0..15 -> cols j0 + tj*4 .. +3
  const int sr = tid >> 2;       // A-staging row 0..63
  const int sc = (tid & 3) * 2;  // A-staging float4 indices sc, sc+1

  float acc[4][4] = {};
  const float4 uv = *(const float4*)(u + j0 + tj * 4);
  const float4 bv = *(const float4*)(b1 + j0 + tj * 4);

  const float4* l4base = (const float4*)(hsl + (size_t)(t0 + sr) * HDIM);
  const float4* r4base = (const float4*)(hsr + (size_t)(t0 + sr) * HDIM);
  const int bj = tid & 63;        // j within tile for B-staging
  const int bkq = tid >> 6;       // 0..3 -> k-quads bkq and bkq+4
  const float* wrow = l1w + (size_t)(j0 + bj) * HDIM;

  float4 ra[2], rb[2], rc0, rc1;
  {  // prologue: panel 0 into registers
#pragma unroll
    for (int i = 0; i < 2; ++i) { ra[i] = l4base[sc + i]; rb[i] = r4base[sc + i]; }
    rc0 = *(const float4*)(wrow + bkq * 4);
    rc1 = *(const float4*)(wrow + (bkq + 4) * 4);
  }

  for (int k0 = 0; k0 < HDIM; k0 += 32) {
    {  // commit registers to LDS
#pragma unroll
      for (int i = 0; i < 2; ++i) {
        As[(sc + i) * 4 + 0][sr] = ra[i].x * rb[i].x;
        As[(sc + i) * 4 + 1][sr] = ra[i].y * rb[i].y;
        As[(sc + i) * 4 + 2][sr] = ra[i].z * rb[i].z;
        As[(sc + i) * 4 + 3][sr] = ra[i].w * rb[i].w;
      }
      Bs[bkq * 4 + 0][bj] = rc0.x;
      Bs[bkq * 4 + 1][bj] = rc0.y;
      Bs[bkq * 4 + 2][bj] = rc0.z;
      Bs[bkq * 4 + 3][bj] = rc0.w;
      Bs[(bkq + 4) * 4 + 0][bj] = rc1.x;
      Bs[(bkq + 4) * 4 + 1][bj] = rc1.y;
      Bs[(bkq + 4) * 4 + 2][bj] = rc1.z;
      Bs[(bkq + 4) * 4 + 3][bj] = rc1.w;
    }
    __syncthreads();
    if (k0 + 32 < HDIM) {  // prefetch next panel; vmcnt stays outstanding over compute
      const int kn = (k0 + 32) / 4;
#pragma unroll
      for (int i = 0; i < 2; ++i) { ra[i] = l4base[kn + sc + i]; rb[i] = r4base[kn + sc + i]; }
      rc0 = *(const float4*)(wrow + k0 + 32 + bkq * 4);
      rc1 = *(const float4*)(wrow + k0 + 32 + (bkq + 4) * 4);
    }
#pragma unroll
    for (int kk = 0; kk < 32; ++kk) {
      float4 a = *(float4*)&As[kk][tm * 4];
      float4 b = *(float4*)&Bs[kk][tj * 4];
      float ar[4] = {a.x, a.y, a.z, a.w};
      float bc[4] = {b.x, b.y, b.z, b.w};
#pragma unroll
      for (int r = 0; r < 4; ++r)
#pragma unroll
        for (int c = 0; c < 4; ++c) acc[r][c] += ar[r] * bc[c];
    }
    __syncthreads();
  }
  // epilogue: pb[r] = sum_c u[j]*tanh(acc + b1[j]); reduce over the 16 tj lanes; atomicAdd
  float ures[4] = {uv.x, uv.y, uv.z, uv.w};
  float bres[4] = {bv.x, bv.y, bv.z, bv.w};
#pragma unroll
  for (int r = 0; r < 4; ++r) {
    float pb = ures[0] * tanhf(acc[r][0] + bres[0]) + ures[1] * tanhf(acc[r][1] + bres[1]) +
               ures[2] * tanhf(acc[r][2] + bres[2]) + ures[3] * tanhf(acc[r][3] + bres[3]);
#pragma unroll
    for (int off = 1; off < 16; off <<= 1) pb += __shfl_xor(pb, off);
    if (tj == 0) atomicAdd(&beta[t0 + tm * 4 + r], pb);
  }
}

// ---------------- svec with fused softmax: s[h] += sum_t softmax(beta)[t]*O[t][h] ----------------
__global__ __launch_bounds__(256) void svec_kernel(const float* __restrict__ beta,
                                                   const float* __restrict__ hsl,
                                                   const float* __restrict__ hsr,
                                                   float* __restrict__ svec, int n) {
  __shared__ float sm[8];
  __shared__ float wts[256];
  __shared__ float red[4][64];
  const int tid = threadIdx.x, lane = tid & 63, wv = tid >> 6;
  // softmax stats over the full beta (small; L2-broadcast across blocks)
  float m = -3.4e38f;
  for (int i = tid; i < n; i += 256) m = fmaxf(m, beta[i]);
  for (int off = 32; off; off >>= 1) m = fmaxf(m, __shfl_xor(m, off));
  if (lane == 0) sm[wv] = m;
  __syncthreads();
  const float M = fmaxf(fmaxf(sm[0], sm[1]), fmaxf(sm[2], sm[3]));
  float z = 0.f;
  for (int i = tid; i < n; i += 256) z += expf(beta[i] - M);
  for (int off = 32; off; off >>= 1) z += __shfl_xor(z, off);
  if (lane == 0) sm[4 + wv] = z;
  __syncthreads();
  const float invZ = 1.f / (sm[4] + sm[5] + sm[6] + sm[7]);
  const int tlen = n / gridDim.y;   // 256 for n=2048, gridDim.y=8
  const int tbeg = blockIdx.y * tlen;
  for (int i = tid; i < tlen; i += 256) wts[i] = expf(beta[tbeg + i] - M) * invZ;
  __syncthreads();
  const int h = blockIdx.x * 64 + lane;
  const int ts = wv;
  float s = 0.f;
  for (int t = ts; t < tlen; t += 4)
    s += wts[t] * hsl[(size_t)(tbeg + t) * HDIM + h] * hsr[(size_t)(tbeg + t) * HDIM + h];
  red[ts][lane] = s;
  __syncthreads();
  if (tid < 64) {
    float tot = red[0][tid] + red[1][tid] + red[2][tid] + red[3][tid];
    atomicAdd(&svec[blockIdx.x * 64 + tid], tot);
  }
}

// ---------------- out[r] = lin2_w[r] . s + lin2_b[r] ----------------
__global__ void final_kernel(const float* __restrict__ svec, const float* __restrict__ l2w,
                             const float* __restrict__ l2b, float* __restrict__ out) {
  int r = threadIdx.x >> 6, lane = threadIdx.x & 63;
  float s = 0.f;
  for (int k = lane; k < HDIM; k += 64) s += l2w[(size_t)r * HDIM + k] * svec[k];
  for (int off = 32; off; off >>= 1) s += __shfl_xor(s, off);
  if (lane == 0) out[r] = s + l2b[r];
}

extern "C" void kernel_launch(void* const* d_in, const int* in_sizes, int n_in,
                              void* d_out, int out_size, void* d_ws, size_t ws_size,
                              hipStream_t stream) {
  const int* x = (const int*)d_in[0];
  const int* tstart = (const int*)d_in[1];
  const int* tend = (const int*)d_in[2];
  const float* emb = (const float*)d_in[3];
  const float* wih_l = (const float*)d_in[4];
  const float* whh_l = (const float*)d_in[5];
  const float* bih_l = (const float*)d_in[6];
  const float* bhh_l = (const float*)d_in[7];
  const float* wih_r = (const float*)d_in[8];
  const float* whh_r = (const float*)d_in[9];
  const float* bih_r = (const float*)d_in[10];
  const float* bhh_r = (const float*)d_in[11];
  const float* l1w = (const float*)d_in[12];
  const float* l1b = (const float*)d_in[13];
  const float* u = (const float*)d_in[14];
  const float* l2w = (const float*)d_in[15];
  const float* l2b = (const float*)d_in[16];
  const int n = in_sizes[0];  // 2048
  (void)n_in; (void)out_size; (void)ws_size;

  float* ws = (float*)d_ws;
  float* target = ws;                     // 1024
  float* seqfl = ws + 1024;               // 1024
  float* seqfr = ws + 2048;               // 1024
  float* glc = ws + 3072;                 // 4096
  float* glf = glc + 4096;                // 4096
  float* grc = glf + 4096;                // 4096
  float* grf = grc + 4096;                // 4096
  u64* hq = (u64*)(grf + 4096);           // 2*1024 u64 (8B aligned)
  float* hsl = (float*)(hq + 2 * HDIM);   // n*1024
  float* hsr = hsl + (size_t)n * HDIM;    // n*1024
  float* beta = hsr + (size_t)n * HDIM;   // n
  float* svec = beta + n;                 // 1024

  setup_kernel<<<1, 1024, 0, stream>>>(x, tstart, tend, emb, target, seqfl, seqfr, hq,
                                       beta, svec, n);
  gateconst_kernel<<<dim3(1024, 2), 256, 0, stream>>>(wih_l, bih_l, bhh_l, wih_r, bih_r, bhh_r,
                                                      target, seqfl, seqfr, glc, glf, grc, grf);
  RecArgs ra;
  ra.whh_l = whh_l; ra.whh_r = whh_r;
  ra.glc = glc; ra.glf = glf; ra.grc = grc; ra.grf = grf;
  ra.hq = hq; ra.hsl = hsl; ra.hsr = hsr;
  ra.pstart = tstart; ra.pend = tend; ra.n = n;
  // Plain launch. Co-residency trivially guaranteed: 128 WGs x 8 waves = 1024 waves
  // << 8192 device capacity.
  rec_kernel<<<dim3(NWG), dim3(TPB), 0, stream>>>(ra);

  beta_gemm_kernel<<<dim3(n / 64, HDIM / 64), 256, 0, stream>>>(hsl, hsr, l1w, l1b, u, beta);
  svec_kernel<<<dim3(16, 8), 256, 0, stream>>>(beta, hsl, hsr, svec, n);
  final_kernel<<<1, 192, 0, stream>>>(svec, l2w, l2b, (float*)d_out);
}